// Round 1
// baseline (112.478 us; speedup 1.0000x reference)
//
#include <hip/hip_runtime.h>
#include <hip/hip_bf16.h>

#define HID 768
#define NB  512
#define NM  3

typedef __bf16 bf16x8 __attribute__((ext_vector_type(8)));
typedef float  f32x4  __attribute__((ext_vector_type(4)));

__device__ __forceinline__ unsigned short f2bf(float f) {
    unsigned u = __builtin_bit_cast(unsigned, f);
    u += 0x7FFFu + ((u >> 16) & 1u);          // round-to-nearest-even
    return (unsigned short)(u >> 16);
}

// C[Mrows,768] = A[Mrows,768] @ W[768,768]^T + bias   (all row-major, K contiguous)
// grid.x = 96 (Q: 8x12 tiles) + 288 (K: 24x12) + 288 (V) = 672, block = 256
__global__ __launch_bounds__(256) void qkv_gemm(
    const float* __restrict__ target, const float* __restrict__ cont,
    const float* __restrict__ Wq, const float* __restrict__ bq,
    const float* __restrict__ Wk, const float* __restrict__ bk,
    const float* __restrict__ Wv, const float* __restrict__ bv,
    float* __restrict__ ws)
{
    const int KO = NB * HID;            // K offset in ws (floats)
    const int VO = KO + NB * NM * HID;  // V offset

    int t = blockIdx.x;
    const float *A, *W, *bias;
    float* C;
    int mtiles;
    if (t < 96)       { A = target; W = Wq; bias = bq; C = ws;      mtiles = 8;  }
    else if (t < 384) { t -= 96;  A = cont; W = Wk; bias = bk; C = ws + KO; mtiles = 24; }
    else              { t -= 384; A = cont; W = Wv; bias = bv; C = ws + VO; mtiles = 24; }
    int tn = t / mtiles, tm = t % mtiles;
    int row0 = tm * 64, col0 = tn * 64;

    // +8 pad per row (40 shorts = 80B) -> frag reads land 16B-aligned, ~2-way banks (free)
    __shared__ alignas(16) unsigned short Al[64][40];
    __shared__ alignas(16) unsigned short Bl[64][40];

    int tid  = threadIdx.x;
    int r    = tid >> 2;          // 0..63  staging row
    int q4   = tid & 3;           // quarter of 32-wide k-slab
    int lane = tid & 63;
    int w    = tid >> 6;          // wave 0..3
    int wm   = (w & 1) * 32, wn = (w >> 1) * 32;
    int fm   = lane & 15;                 // frag row (A) / col (B)
    int kof  = (lane >> 4) * 8;           // frag k-offset (quad*8)

    f32x4 acc00 = {0.f,0.f,0.f,0.f};
    f32x4 acc01 = acc00, acc10 = acc00, acc11 = acc00;

    const float* Arow = A + (size_t)(row0 + r) * HID + q4 * 8;
    const float* Wrow = W + (size_t)(col0 + r) * HID + q4 * 8;

    for (int k0 = 0; k0 < HID; k0 += 32) {
        float4 a0 = *(const float4*)(Arow + k0);
        float4 a1 = *(const float4*)(Arow + k0 + 4);
        float4 b0 = *(const float4*)(Wrow + k0);
        float4 b1 = *(const float4*)(Wrow + k0 + 4);
        unsigned short ta[8] = { f2bf(a0.x), f2bf(a0.y), f2bf(a0.z), f2bf(a0.w),
                                 f2bf(a1.x), f2bf(a1.y), f2bf(a1.z), f2bf(a1.w) };
        unsigned short tb[8] = { f2bf(b0.x), f2bf(b0.y), f2bf(b0.z), f2bf(b0.w),
                                 f2bf(b1.x), f2bf(b1.y), f2bf(b1.z), f2bf(b1.w) };
        __syncthreads();   // prev iteration's frag reads done before overwrite
        *(uint4*)&Al[r][q4 * 8] = *(uint4*)ta;
        *(uint4*)&Bl[r][q4 * 8] = *(uint4*)tb;
        __syncthreads();

        bf16x8 af0 = *(const bf16x8*)&Al[wm + fm][kof];
        bf16x8 af1 = *(const bf16x8*)&Al[wm + 16 + fm][kof];
        bf16x8 bf0 = *(const bf16x8*)&Bl[wn + fm][kof];
        bf16x8 bf1 = *(const bf16x8*)&Bl[wn + 16 + fm][kof];
        acc00 = __builtin_amdgcn_mfma_f32_16x16x32_bf16(af0, bf0, acc00, 0, 0, 0);
        acc01 = __builtin_amdgcn_mfma_f32_16x16x32_bf16(af0, bf1, acc01, 0, 0, 0);
        acc10 = __builtin_amdgcn_mfma_f32_16x16x32_bf16(af1, bf0, acc10, 0, 0, 0);
        acc11 = __builtin_amdgcn_mfma_f32_16x16x32_bf16(af1, bf1, acc11, 0, 0, 0);
    }

    // C/D layout (verified m89/m91): col = lane&15, row = (lane>>4)*4 + reg
    int crow = row0 + wm + (lane >> 4) * 4;
    int ccol = col0 + wn + fm;
    float bb0 = bias[ccol], bb1 = bias[ccol + 16];
    #pragma unroll
    for (int rg = 0; rg < 4; rg++) {
        C[(size_t)(crow + rg)      * HID + ccol]      = acc00[rg] + bb0;
        C[(size_t)(crow + rg)      * HID + ccol + 16] = acc01[rg] + bb1;
        C[(size_t)(crow + 16 + rg) * HID + ccol]      = acc10[rg] + bb0;
        C[(size_t)(crow + 16 + rg) * HID + ccol + 16] = acc11[rg] + bb1;
    }
}

// Per-batch epilogue: kernel_v, kernel_r, Gram S, then output. grid = 512, block = 256
__global__ __launch_bounds__(256) void finalize(
    const float* __restrict__ ws, const float* __restrict__ p,
    const float* __restrict__ hmat, const float* __restrict__ g,
    float* __restrict__ out)
{
    const int KO = NB * HID;
    const int VO = KO + NB * NM * HID;
    int b    = blockIdx.x;
    int tid  = threadIdx.x;
    int lane = tid & 63;
    int wv   = tid >> 6;

    const float* q  = ws + (size_t)b * HID;
    const float* kk = ws + KO + (size_t)b * NM * HID;
    const float* vv = ws + VO + (size_t)b * NM * HID;

    // acc: [0..2]=kernel_v, [3..5]=kernel_r, [6..11]=S upper triangle (00,01,02,11,12,22)
    float acc[12];
    #pragma unroll
    for (int i = 0; i < 12; i++) acc[i] = 0.f;

    for (int h0 = tid; h0 < HID; h0 += 256) {
        float qh = q[h0];
        float k0 = kk[h0], k1 = kk[HID + h0], k2 = kk[2 * HID + h0];
        float v0 = vv[h0], v1 = vv[HID + h0], v2 = vv[2 * HID + h0];
        acc[0] += p[h0] * qh;
        acc[1] += p[HID + h0] * qh;
        acc[2] += p[2 * HID + h0] * qh;
        float x0 = qh * k0, x1 = qh * k1, x2 = qh * k2;
        const float* h0p = hmat + (size_t)h0 * 3;             // h[(0*H+h), j]
        const float* h1p = hmat + (size_t)(HID + h0) * 3;
        const float* h2p = hmat + (size_t)(2 * HID + h0) * 3;
        acc[3] += x0 * h0p[0] + x1 * h1p[0] + x2 * h2p[0];
        acc[4] += x0 * h0p[1] + x1 * h1p[1] + x2 * h2p[1];
        acc[5] += x0 * h0p[2] + x1 * h1p[2] + x2 * h2p[2];
        acc[6]  += v0 * v0; acc[7]  += v0 * v1; acc[8]  += v0 * v2;
        acc[9]  += v1 * v1; acc[10] += v1 * v2; acc[11] += v2 * v2;
    }

    #pragma unroll
    for (int i = 0; i < 12; i++)
        #pragma unroll
        for (int off = 32; off > 0; off >>= 1)
            acc[i] += __shfl_down(acc[i], off);

    __shared__ float sred[12][4];
    __shared__ float fin[12];
    if (lane == 0) {
        #pragma unroll
        for (int i = 0; i < 12; i++) sred[i][wv] = acc[i];
    }
    __syncthreads();
    if (tid < 12) fin[tid] = sred[tid][0] + sred[tid][1] + sred[tid][2] + sred[tid][3];
    __syncthreads();

    float kern0 = fin[0] + fin[3], kern1 = fin[1] + fin[4], kern2 = fin[2] + fin[5];
    float S00 = fin[6], S01 = fin[7], S02 = fin[8];
    float S11 = fin[9], S12 = fin[10], S22 = fin[11];

    for (int c = tid; c < HID; c += 256) {
        float g0 = g[c], g1 = g[HID + c], g2 = g[2 * HID + c];
        float v0 = vv[c], v1 = vv[HID + c], v2 = vv[2 * HID + c];
        float c0 = S00 * g0 + S01 * g1 + S02 * g2 + v0;
        float c1 = S01 * g0 + S11 * g1 + S12 * g2 + v1;
        float c2 = S02 * g0 + S12 * g1 + S22 * g2 + v2;
        out[(size_t)b * HID + c] = kern0 * c0 + kern1 * c1 + kern2 * c2;
    }
}

extern "C" void kernel_launch(void* const* d_in, const int* in_sizes, int n_in,
                              void* d_out, int out_size, void* d_ws, size_t ws_size,
                              hipStream_t stream) {
    (void)in_sizes; (void)n_in; (void)out_size; (void)ws_size;
    const float* target = (const float*)d_in[0];
    const float* cont   = (const float*)d_in[1];
    const float* Wq     = (const float*)d_in[2];
    const float* bq     = (const float*)d_in[3];
    const float* Wk     = (const float*)d_in[4];
    const float* bk     = (const float*)d_in[5];
    const float* Wv     = (const float*)d_in[6];
    const float* bv     = (const float*)d_in[7];
    const float* p      = (const float*)d_in[8];
    const float* hmat   = (const float*)d_in[9];
    const float* g      = (const float*)d_in[10];
    float* ws  = (float*)d_ws;
    float* out = (float*)d_out;

    qkv_gemm<<<672, 256, 0, stream>>>(target, cont, Wq, bq, Wk, bk, Wv, bv, ws);
    finalize<<<512, 256, 0, stream>>>(ws, p, hmat, g, out);
}

// Round 2
// 102.728 us; speedup vs baseline: 1.0949x; 1.0949x over previous
//
#include <hip/hip_runtime.h>
#include <hip/hip_bf16.h>

#define HID 768
#define NB  512
#define NM  3

typedef __bf16 bf16x8 __attribute__((ext_vector_type(8)));
typedef float  f32x4  __attribute__((ext_vector_type(4)));

// ---- ws layout (element offsets) ----
// bf16 region:  Abf [2048x768]  at 0            (rows 0-511 target, 512-2047 cont)
//               Wbf [2304x768]  at 1572864      (Wq | Wk | Wv stacked)
// fp32 region:  Q [512x768], K [1536x768], V [1536x768] starting at float ofs 1671168
#define WBF_OFF   1572864
#define QKV_OFF   1671168
#define QN        393216      // 512*768
#define KVN       1179648     // 1536*768

__device__ __forceinline__ unsigned short f2bf(float f) {
    unsigned u = __builtin_bit_cast(unsigned, f);
    u += 0x7FFFu + ((u >> 16) & 1u);          // round-to-nearest-even
    return (unsigned short)(u >> 16);
}

__device__ __forceinline__ void async_cp16(const void* g, void* l) {
    __builtin_amdgcn_global_load_lds(
        (const __attribute__((address_space(1))) void*)g,
        (__attribute__((address_space(3))) void*)l, 16, 0, 0);
}

// ---- fp32 -> bf16 conversion of all GEMM operands, one pass ----
// float4 units: target 98304 | cont 294912 | Wq 147456 | Wk 147456 | Wv 147456
// total 835584 units = 3264 blocks x 256
__global__ __launch_bounds__(256) void cvt(
    const float4* __restrict__ t, const float4* __restrict__ c,
    const float4* __restrict__ wq, const float4* __restrict__ wk,
    const float4* __restrict__ wv, ushort4* __restrict__ abf,
    ushort4* __restrict__ wbf)
{
    int i = blockIdx.x * 256 + threadIdx.x;
    float4 v;
    ushort4* d;
    if (i < 393216) {
        v = (i < 98304) ? t[i] : c[i - 98304];
        d = abf + i;
    } else {
        int j = i - 393216;
        v = (j < 147456) ? wq[j] : (j < 294912 ? wk[j - 147456] : wv[j - 294912]);
        d = wbf + j;
    }
    ushort4 o = { f2bf(v.x), f2bf(v.y), f2bf(v.z), f2bf(v.w) };
    *d = o;
}

// ---- bf16 MFMA GEMM: C[rows,768] = A @ W^T + bias, 64x64 tiles ----
// grid = 96 (Q) + 288 (K) + 288 (V) = 672 blocks, 256 threads
__global__ __launch_bounds__(256) void qkv_gemm(
    const unsigned short* __restrict__ bf, float* __restrict__ wsf,
    const float* __restrict__ bq, const float* __restrict__ bk,
    const float* __restrict__ bv)
{
    const unsigned short* Ab = bf;               // 2048x768
    const unsigned short* Wb = bf + WBF_OFF;     // 2304x768
    float* Qf = wsf + QKV_OFF;
    float* Kf = Qf + QN;
    float* Vf = Kf + KVN;

    int t = blockIdx.x;
    const unsigned short *A, *W;
    const float* bias;
    float* C;
    int mtiles;
    if (t < 96)       {          A = Ab;             W = Wb;              bias = bq; C = Qf; mtiles = 8;  }
    else if (t < 384) { t -= 96; A = Ab + 512 * HID; W = Wb + 768 * HID;  bias = bk; C = Kf; mtiles = 24; }
    else              { t -= 384; A = Ab + 512 * HID; W = Wb + 1536 * HID; bias = bv; C = Vf; mtiles = 24; }
    int tn = t / mtiles, tm = t % mtiles;
    int row0 = tm * 64, col0 = tn * 64;

    // NO padding: global_load_lds writes wave-uniform base + lane*16
    __shared__ unsigned short Al[64][32];
    __shared__ unsigned short Bl[64][32];

    int tid  = threadIdx.x;
    int l    = tid & 63;
    int w    = tid >> 6;
    int srow = tid >> 2;          // 0..63
    int scol = (tid & 3) * 8;     // k-offset within 32-slab

    const unsigned short* ga = A + (size_t)(row0 + srow) * HID + scol;
    const unsigned short* gb = W + (size_t)(col0 + srow) * HID + scol;
    char* la = (char*)&Al[0][0] + w * 1024;   // wave w stages rows w*16..w*16+15
    char* lb = (char*)&Bl[0][0] + w * 1024;

    int wm = (w & 1) * 32, wn = (w >> 1) * 32;
    int fm = l & 15, kof = (l >> 4) * 8;

    f32x4 acc00 = {0.f, 0.f, 0.f, 0.f};
    f32x4 acc01 = acc00, acc10 = acc00, acc11 = acc00;

    for (int k0 = 0; k0 < HID; k0 += 32) {
        __syncthreads();                 // prev iter's frag reads complete
        async_cp16(ga, la);
        async_cp16(gb, lb);
        ga += 32; gb += 32;
        __syncthreads();                 // drains vmcnt -> LDS data visible

        bf16x8 af0 = *(const bf16x8*)&Al[wm + fm][kof];
        bf16x8 af1 = *(const bf16x8*)&Al[wm + 16 + fm][kof];
        bf16x8 bf0 = *(const bf16x8*)&Bl[wn + fm][kof];
        bf16x8 bf1 = *(const bf16x8*)&Bl[wn + 16 + fm][kof];
        acc00 = __builtin_amdgcn_mfma_f32_16x16x32_bf16(af0, bf0, acc00, 0, 0, 0);
        acc01 = __builtin_amdgcn_mfma_f32_16x16x32_bf16(af0, bf1, acc01, 0, 0, 0);
        acc10 = __builtin_amdgcn_mfma_f32_16x16x32_bf16(af1, bf0, acc10, 0, 0, 0);
        acc11 = __builtin_amdgcn_mfma_f32_16x16x32_bf16(af1, bf1, acc11, 0, 0, 0);
    }

    // C/D layout (verified m89/m91): col = lane&15, row = (lane>>4)*4 + reg
    int crow = row0 + wm + (l >> 4) * 4;
    int ccol = col0 + wn + fm;
    float bb0 = bias[ccol], bb1 = bias[ccol + 16];
    #pragma unroll
    for (int rg = 0; rg < 4; rg++) {
        C[(size_t)(crow + rg)      * HID + ccol]      = acc00[rg] + bb0;
        C[(size_t)(crow + rg)      * HID + ccol + 16] = acc01[rg] + bb1;
        C[(size_t)(crow + 16 + rg) * HID + ccol]      = acc10[rg] + bb0;
        C[(size_t)(crow + 16 + rg) * HID + ccol + 16] = acc11[rg] + bb1;
    }
}

// ---- per-batch epilogue ----
__global__ __launch_bounds__(256) void finalize(
    const float* __restrict__ wsf, const float* __restrict__ p,
    const float* __restrict__ hmat, const float* __restrict__ g,
    float* __restrict__ out)
{
    int b    = blockIdx.x;
    int tid  = threadIdx.x;
    int lane = tid & 63;
    int wv   = tid >> 6;

    const float* q  = wsf + QKV_OFF + (size_t)b * HID;
    const float* kk = wsf + QKV_OFF + QN + (size_t)b * NM * HID;
    const float* vv = kk + KVN;

    // acc: [0..2]=kernel_v, [3..5]=kernel_r, [6..11]=S (00,01,02,11,12,22)
    float acc[12];
    #pragma unroll
    for (int i = 0; i < 12; i++) acc[i] = 0.f;

    for (int h0 = tid; h0 < HID; h0 += 256) {
        float qh = q[h0];
        float k0 = kk[h0], k1 = kk[HID + h0], k2 = kk[2 * HID + h0];
        float v0 = vv[h0], v1 = vv[HID + h0], v2 = vv[2 * HID + h0];
        acc[0] += p[h0] * qh;
        acc[1] += p[HID + h0] * qh;
        acc[2] += p[2 * HID + h0] * qh;
        float x0 = qh * k0, x1 = qh * k1, x2 = qh * k2;
        const float* h0p = hmat + (size_t)h0 * 3;
        const float* h1p = hmat + (size_t)(HID + h0) * 3;
        const float* h2p = hmat + (size_t)(2 * HID + h0) * 3;
        acc[3] += x0 * h0p[0] + x1 * h1p[0] + x2 * h2p[0];
        acc[4] += x0 * h0p[1] + x1 * h1p[1] + x2 * h2p[1];
        acc[5] += x0 * h0p[2] + x1 * h1p[2] + x2 * h2p[2];
        acc[6]  += v0 * v0; acc[7]  += v0 * v1; acc[8]  += v0 * v2;
        acc[9]  += v1 * v1; acc[10] += v1 * v2; acc[11] += v2 * v2;
    }

    #pragma unroll
    for (int i = 0; i < 12; i++)
        #pragma unroll
        for (int off = 32; off > 0; off >>= 1)
            acc[i] += __shfl_down(acc[i], off);

    __shared__ float sred[12][4];
    __shared__ float fin[12];
    if (lane == 0) {
        #pragma unroll
        for (int i = 0; i < 12; i++) sred[i][wv] = acc[i];
    }
    __syncthreads();
    if (tid < 12) fin[tid] = sred[tid][0] + sred[tid][1] + sred[tid][2] + sred[tid][3];
    __syncthreads();

    float kern0 = fin[0] + fin[3], kern1 = fin[1] + fin[4], kern2 = fin[2] + fin[5];
    float S00 = fin[6], S01 = fin[7], S02 = fin[8];
    float S11 = fin[9], S12 = fin[10], S22 = fin[11];

    for (int c = tid; c < HID; c += 256) {
        float g0 = g[c], g1 = g[HID + c], g2 = g[2 * HID + c];
        float v0 = vv[c], v1 = vv[HID + c], v2 = vv[2 * HID + c];
        float c0 = S00 * g0 + S01 * g1 + S02 * g2 + v0;
        float c1 = S01 * g0 + S11 * g1 + S12 * g2 + v1;
        float c2 = S02 * g0 + S12 * g1 + S22 * g2 + v2;
        out[(size_t)b * HID + c] = kern0 * c0 + kern1 * c1 + kern2 * c2;
    }
}

extern "C" void kernel_launch(void* const* d_in, const int* in_sizes, int n_in,
                              void* d_out, int out_size, void* d_ws, size_t ws_size,
                              hipStream_t stream) {
    (void)in_sizes; (void)n_in; (void)out_size; (void)ws_size;
    const float* target = (const float*)d_in[0];
    const float* cont   = (const float*)d_in[1];
    const float* Wq     = (const float*)d_in[2];
    const float* bq     = (const float*)d_in[3];
    const float* Wk     = (const float*)d_in[4];
    const float* bk     = (const float*)d_in[5];
    const float* Wv     = (const float*)d_in[6];
    const float* bv     = (const float*)d_in[7];
    const float* p      = (const float*)d_in[8];
    const float* hmat   = (const float*)d_in[9];
    const float* g      = (const float*)d_in[10];

    unsigned short* bfreg = (unsigned short*)d_ws;
    float* wsf = (float*)d_ws;
    float* out = (float*)d_out;

    cvt<<<3264, 256, 0, stream>>>((const float4*)target, (const float4*)cont,
                                  (const float4*)Wq, (const float4*)Wk, (const float4*)Wv,
                                  (ushort4*)bfreg, (ushort4*)(bfreg + WBF_OFF));
    qkv_gemm<<<672, 256, 0, stream>>>(bfreg, wsf, bq, bk, bv);
    finalize<<<512, 256, 0, stream>>>(wsf, p, hmat, g, out);
}

// Round 3
// 102.237 us; speedup vs baseline: 1.1002x; 1.0048x over previous
//
#include <hip/hip_runtime.h>
#include <hip/hip_bf16.h>

#define HID 768
#define NB  512
#define NM  3

typedef __bf16 bf16x8 __attribute__((ext_vector_type(8)));
typedef float  f32x4  __attribute__((ext_vector_type(4)));

// ---- ws layout (element offsets) ----
// bf16: Abf [2048x768] at 0 (rows 0-511 target, 512-2047 cont)
//       Wbf [2304x768] at 1572864 (Wq | Wk | Wv)
// fp32: Q [512x768], K [1536x768], V [1536x768] from float ofs 1671168
#define WBF_OFF   1572864
#define QKV_OFF   1671168
#define QN        393216
#define KVN       1179648

__device__ __forceinline__ unsigned short f2bf(float f) {
    unsigned u = __builtin_bit_cast(unsigned, f);
    u += 0x7FFFu + ((u >> 16) & 1u);          // RNE
    return (unsigned short)(u >> 16);
}

__device__ __forceinline__ void async_cp16(const void* g, void* l) {
    __builtin_amdgcn_global_load_lds(
        (const __attribute__((address_space(1))) void*)g,
        (__attribute__((address_space(3))) void*)l, 16, 0, 0);
}

// ---- fp32 -> bf16 conversion, one streaming pass (3264 x 256) ----
__global__ __launch_bounds__(256) void cvt(
    const float4* __restrict__ t, const float4* __restrict__ c,
    const float4* __restrict__ wq, const float4* __restrict__ wk,
    const float4* __restrict__ wv, ushort4* __restrict__ abf,
    ushort4* __restrict__ wbf)
{
    int i = blockIdx.x * 256 + threadIdx.x;
    float4 v;
    ushort4* d;
    if (i < 393216) {
        v = (i < 98304) ? t[i] : c[i - 98304];
        d = abf + i;
    } else {
        int j = i - 393216;
        v = (j < 147456) ? wq[j] : (j < 294912 ? wk[j - 147456] : wv[j - 294912]);
        d = wbf + j;
    }
    ushort4 o = { f2bf(v.x), f2bf(v.y), f2bf(v.z), f2bf(v.w) };
    *d = o;
}

// ---- bf16 MFMA GEMM: C[rows,768] = A @ W^T + bias ----
// 64x64 tiles, BK=128, 2-stage LDS pipeline, XOR-swizzled LDS (conflict-free)
// grid = 96 (Q) + 288 (K) + 288 (V) = 672 blocks, 256 threads
__global__ __launch_bounds__(256) void qkv_gemm(
    const unsigned short* __restrict__ bfp, float* __restrict__ wsf,
    const float* __restrict__ bq, const float* __restrict__ bk,
    const float* __restrict__ bv)
{
    const unsigned short* Ab = bfp;               // 2048x768
    const unsigned short* Wb = bfp + WBF_OFF;     // 2304x768
    float* Qf = wsf + QKV_OFF;
    float* Kf = Qf + QN;
    float* Vf = Kf + KVN;

    int t = blockIdx.x;
    const unsigned short *A, *W;
    const float* bias;
    float* C;
    int mtiles;
    if (t < 96)       {          A = Ab;              W = Wb;              bias = bq; C = Qf; mtiles = 8;  }
    else if (t < 384) { t -= 96;  A = Ab + 512 * HID; W = Wb + 768 * HID;  bias = bk; C = Kf; mtiles = 24; }
    else              { t -= 384; A = Ab + 512 * HID; W = Wb + 1536 * HID; bias = bv; C = Vf; mtiles = 24; }
    int tn = t / mtiles, tm = t % mtiles;
    int row0 = tm * 64, col0 = tn * 64;

    // stage s: A tile at s*32768, B tile at s*32768+16384 (bytes). 64 KB total.
    __shared__ __align__(16) unsigned short lds[32768];
    char* ldsb = (char*)lds;

    int tid  = threadIdx.x;
    int lane = tid & 63;
    int w    = tid >> 6;
    int q    = lane >> 4;        // quad 0..3
    int fm   = lane & 15;

    // Staging: instruction j of wave w covers LDS bytes [j*4096 + w*1024, +1024)
    // -> row r = j*16 + w*4 + q, 16B-slot c = fm. Slot c of row r holds global
    // k-chunk g = c ^ (r&15)  (XOR swizzle => conflict-free frag reads).
    const unsigned short* gA[4];
    const unsigned short* gB[4];
    #pragma unroll
    for (int j = 0; j < 4; j++) {
        int r = j * 16 + w * 4 + q;
        int g = fm ^ (r & 15);
        gA[j] = A + (size_t)(row0 + r) * HID + g * 8;
        gB[j] = W + (size_t)(col0 + r) * HID + g * 8;
    }

    int wm = (w & 1) * 32, wn = (w >> 1) * 32;

    f32x4 acc00 = {0.f, 0.f, 0.f, 0.f};
    f32x4 acc01 = acc00, acc10 = acc00, acc11 = acc00;

    #define STAGE_LOAD(s, kc)                                            \
        {                                                                \
            char* bA_ = ldsb + (s) * 32768;                              \
            char* bB_ = bA_ + 16384;                                     \
            int ko_ = (kc) * 128;                                        \
            _Pragma("unroll")                                            \
            for (int j = 0; j < 4; j++) {                                \
                async_cp16(gA[j] + ko_, bA_ + j * 4096 + w * 1024);      \
                async_cp16(gB[j] + ko_, bB_ + j * 4096 + w * 1024);      \
            }                                                            \
        }

    STAGE_LOAD(0, 0)
    STAGE_LOAD(1, 1)
    __syncthreads();

    #pragma unroll
    for (int c = 0; c < 6; c++) {
        int s = c & 1;
        char* bA = ldsb + s * 32768;
        char* bB = bA + 16384;
        #pragma unroll
        for (int s4 = 0; s4 < 4; s4++) {
            int slot = ((4 * s4 + q) ^ fm) * 16;     // de-swizzle
            bf16x8 af0 = *(const bf16x8*)(bA + (wm + fm) * 256 + slot);
            bf16x8 af1 = *(const bf16x8*)(bA + (wm + 16 + fm) * 256 + slot);
            bf16x8 bf0 = *(const bf16x8*)(bB + (wn + fm) * 256 + slot);
            bf16x8 bf1 = *(const bf16x8*)(bB + (wn + 16 + fm) * 256 + slot);
            acc00 = __builtin_amdgcn_mfma_f32_16x16x32_bf16(af0, bf0, acc00, 0, 0, 0);
            acc01 = __builtin_amdgcn_mfma_f32_16x16x32_bf16(af0, bf1, acc01, 0, 0, 0);
            acc10 = __builtin_amdgcn_mfma_f32_16x16x32_bf16(af1, bf0, acc10, 0, 0, 0);
            acc11 = __builtin_amdgcn_mfma_f32_16x16x32_bf16(af1, bf1, acc11, 0, 0, 0);
        }
        if (c < 4) {
            __syncthreads();            // readers of buf s done; drains prev load
            STAGE_LOAD(s, c + 2)
        } else if (c == 4) {
            __syncthreads();            // drain chunk-5 load before last compute
        }
    }
    #undef STAGE_LOAD

    // C/D layout (m89/m91): col = lane&15, row = (lane>>4)*4 + reg
    int crow = row0 + wm + q * 4;
    int ccol = col0 + wn + fm;
    float bb0 = bias[ccol], bb1 = bias[ccol + 16];
    #pragma unroll
    for (int rg = 0; rg < 4; rg++) {
        C[(size_t)(crow + rg)      * HID + ccol]      = acc00[rg] + bb0;
        C[(size_t)(crow + rg)      * HID + ccol + 16] = acc01[rg] + bb1;
        C[(size_t)(crow + 16 + rg) * HID + ccol]      = acc10[rg] + bb0;
        C[(size_t)(crow + 16 + rg) * HID + ccol + 16] = acc11[rg] + bb1;
    }
}

// ---- per-batch epilogue (512 x 256) ----
__global__ __launch_bounds__(256) void finalize(
    const float* __restrict__ wsf, const float* __restrict__ p,
    const float* __restrict__ hmat, const float* __restrict__ g,
    float* __restrict__ out)
{
    int b    = blockIdx.x;
    int tid  = threadIdx.x;
    int lane = tid & 63;
    int wv   = tid >> 6;

    const float* qrow = wsf + QKV_OFF + (size_t)b * HID;
    const float* kk   = wsf + QKV_OFF + QN + (size_t)b * NM * HID;
    const float* vv   = kk + KVN;

    float acc[12];
    #pragma unroll
    for (int i = 0; i < 12; i++) acc[i] = 0.f;

    for (int h0 = tid; h0 < HID; h0 += 256) {
        float qh = qrow[h0];
        float k0 = kk[h0], k1 = kk[HID + h0], k2 = kk[2 * HID + h0];
        float v0 = vv[h0], v1 = vv[HID + h0], v2 = vv[2 * HID + h0];
        acc[0] += p[h0] * qh;
        acc[1] += p[HID + h0] * qh;
        acc[2] += p[2 * HID + h0] * qh;
        float x0 = qh * k0, x1 = qh * k1, x2 = qh * k2;
        const float* h0p = hmat + (size_t)h0 * 3;
        const float* h1p = hmat + (size_t)(HID + h0) * 3;
        const float* h2p = hmat + (size_t)(2 * HID + h0) * 3;
        acc[3] += x0 * h0p[0] + x1 * h1p[0] + x2 * h2p[0];
        acc[4] += x0 * h0p[1] + x1 * h1p[1] + x2 * h2p[1];
        acc[5] += x0 * h0p[2] + x1 * h1p[2] + x2 * h2p[2];
        acc[6]  += v0 * v0; acc[7]  += v0 * v1; acc[8]  += v0 * v2;
        acc[9]  += v1 * v1; acc[10] += v1 * v2; acc[11] += v2 * v2;
    }

    #pragma unroll
    for (int i = 0; i < 12; i++)
        #pragma unroll
        for (int off = 32; off > 0; off >>= 1)
            acc[i] += __shfl_down(acc[i], off);

    __shared__ float sred[12][4];
    __shared__ float fin[12];
    if (lane == 0) {
        #pragma unroll
        for (int i = 0; i < 12; i++) sred[i][wv] = acc[i];
    }
    __syncthreads();
    if (tid < 12) fin[tid] = sred[tid][0] + sred[tid][1] + sred[tid][2] + sred[tid][3];
    __syncthreads();

    float kern0 = fin[0] + fin[3], kern1 = fin[1] + fin[4], kern2 = fin[2] + fin[5];
    float S00 = fin[6], S01 = fin[7], S02 = fin[8];
    float S11 = fin[9], S12 = fin[10], S22 = fin[11];

    for (int cc = tid; cc < HID; cc += 256) {
        float g0 = g[cc], g1 = g[HID + cc], g2 = g[2 * HID + cc];
        float v0 = vv[cc], v1 = vv[HID + cc], v2 = vv[2 * HID + cc];
        float c0 = S00 * g0 + S01 * g1 + S02 * g2 + v0;
        float c1 = S01 * g0 + S11 * g1 + S12 * g2 + v1;
        float c2 = S02 * g0 + S12 * g1 + S22 * g2 + v2;
        out[(size_t)b * HID + cc] = kern0 * c0 + kern1 * c1 + kern2 * c2;
    }
}

extern "C" void kernel_launch(void* const* d_in, const int* in_sizes, int n_in,
                              void* d_out, int out_size, void* d_ws, size_t ws_size,
                              hipStream_t stream) {
    (void)in_sizes; (void)n_in; (void)out_size; (void)ws_size;
    const float* target = (const float*)d_in[0];
    const float* cont   = (const float*)d_in[1];
    const float* Wq     = (const float*)d_in[2];
    const float* bq     = (const float*)d_in[3];
    const float* Wk     = (const float*)d_in[4];
    const float* bk     = (const float*)d_in[5];
    const float* Wv     = (const float*)d_in[6];
    const float* bv     = (const float*)d_in[7];
    const float* p      = (const float*)d_in[8];
    const float* hmat   = (const float*)d_in[9];
    const float* g      = (const float*)d_in[10];

    unsigned short* bfreg = (unsigned short*)d_ws;
    float* wsf = (float*)d_ws;
    float* out = (float*)d_out;

    cvt<<<3264, 256, 0, stream>>>((const float4*)target, (const float4*)cont,
                                  (const float4*)Wq, (const float4*)Wk, (const float4*)Wv,
                                  (ushort4*)bfreg, (ushort4*)(bfreg + WBF_OFF));
    qkv_gemm<<<672, 256, 0, stream>>>(bfreg, wsf, bq, bk, bv);
    finalize<<<512, 256, 0, stream>>>(wsf, p, hmat, g, out);
}